// Round 5
// baseline (119.970 us; speedup 1.0000x reference)
//
#include <hip/hip_runtime.h>
#include <math.h>

typedef float f32x4 __attribute__((ext_vector_type(4)));
typedef short s16x8 __attribute__((ext_vector_type(8)));

#define NROWS 8192
#define NCOLS 512
#define BHALF 4096
#define NT    64       // 8192 / 128 tiles per dim
#define BM    128
#define NBLK  (NT * (NT + 1) / 2)   // 2080 triangular tiles (2080 % 8 == 0)
#define CSPART 256                   // colsum partial blocks

typedef __attribute__((address_space(1))) const unsigned int guint;
typedef __attribute__((address_space(3))) unsigned int luint;

// ---------- helpers ----------
__device__ __forceinline__ unsigned short f2bf(float f) {
    // RNE float -> bf16 (inputs are finite normals; no NaN handling needed)
    unsigned u = __builtin_bit_cast(unsigned, f);
    u += 0x7FFFu + ((u >> 16) & 1u);
    return (unsigned short)(u >> 16);
}

// ---------- fused conversion + row-sq + colsum partials ----------
// 256 blocks x 256 threads; block covers 32 rows (8 rows per wave).
// Deterministic: all reductions fixed-order, no atomics.
__global__ void k_conv(const float* __restrict__ src, const float* __restrict__ tgt,
                       short* __restrict__ bfall, float* __restrict__ sq,
                       float* __restrict__ cspart) {
    __shared__ float colp[4][NCOLS];
    int t = threadIdx.x, w = t >> 6, l = t & 63;
    int r0 = blockIdx.x * 32 + w * 8;
    float c0x=0.f,c0y=0.f,c0z=0.f,c0w=0.f, c1x=0.f,c1y=0.f,c1z=0.f,c1w=0.f;
    #pragma unroll
    for (int r = 0; r < 8; ++r) {
        int row = r0 + r;
        const float* base = (row < BHALF) ? (src + (size_t)row * NCOLS)
                                          : (tgt + (size_t)(row - BHALF) * NCOLS);
        float4 a = ((const float4*)base)[2 * l];
        float4 b = ((const float4*)base)[2 * l + 1];
        s16x8 v;
        v[0] = (short)f2bf(a.x); v[1] = (short)f2bf(a.y);
        v[2] = (short)f2bf(a.z); v[3] = (short)f2bf(a.w);
        v[4] = (short)f2bf(b.x); v[5] = (short)f2bf(b.y);
        v[6] = (short)f2bf(b.z); v[7] = (short)f2bf(b.w);
        ((s16x8*)(bfall + (size_t)row * NCOLS))[l] = v;
        float s = a.x*a.x + a.y*a.y + a.z*a.z + a.w*a.w
                + b.x*b.x + b.y*b.y + b.z*b.z + b.w*b.w;
        #pragma unroll
        for (int o = 32; o > 0; o >>= 1) s += __shfl_down(s, o);
        if (l == 0) sq[row] = s;
        c0x += a.x; c0y += a.y; c0z += a.z; c0w += a.w;
        c1x += b.x; c1y += b.y; c1z += b.z; c1w += b.w;
    }
    colp[w][l*8+0] = c0x; colp[w][l*8+1] = c0y; colp[w][l*8+2] = c0z; colp[w][l*8+3] = c0w;
    colp[w][l*8+4] = c1x; colp[w][l*8+5] = c1y; colp[w][l*8+6] = c1z; colp[w][l*8+7] = c1w;
    __syncthreads();
    float s0 = colp[0][t] + colp[1][t] + colp[2][t] + colp[3][t];
    float s1 = colp[0][t+256] + colp[1][t+256] + colp[2][t+256] + colp[3][t+256];
    cspart[(size_t)blockIdx.x * NCOLS + t]       = s0;
    cspart[(size_t)blockIdx.x * NCOLS + t + 256] = s1;
}

// bandwidth from analytic sum(l2) = 2n*T - 2*||colsum||^2 ; store log2(e)/bw_k
// fully fixed-order -> deterministic
__global__ void k_bw(const float* __restrict__ sq, const float* __restrict__ colsum_part,
                     float* __restrict__ cvals) {
    __shared__ double red[512];
    __shared__ double sT;
    int t = threadIdx.x;
    double acc = 0.0;
    for (int i = t; i < NROWS; i += 512) acc += (double)sq[i];
    red[t] = acc; __syncthreads();
    for (int o = 256; o > 0; o >>= 1) { if (t < o) red[t] += red[t + o]; __syncthreads(); }
    if (t == 0) sT = red[0];
    __syncthreads();
    double c = 0.0;
    for (int p = 0; p < CSPART; ++p) c += (double)colsum_part[(size_t)p * NCOLS + t];
    red[t] = c * c; __syncthreads();
    for (int o = 256; o > 0; o >>= 1) { if (t < o) red[t] += red[t + o]; __syncthreads(); }
    if (t == 0) {
        double G = red[0];
        double sum_l2 = 2.0 * (double)NROWS * sT - 2.0 * G;
        double denom = (double)NROWS * (double)NROWS - (double)NROWS;
        double bw = sum_l2 / denom / 4.0;   // KERNEL_MUL^(KERNEL_NUM/2) = 4
        const double L2E = 1.4426950408889634;
        double b = bw;
        #pragma unroll
        for (int k = 0; k < 5; ++k) { cvals[k] = (float)(L2E / b); b *= 2.0; }
    }
}

// ---------- main fused MMD kernel ----------
// 128x128 tile per block, 4 waves (2x2), wave tile 64x64 via 4x4 of 16x16x32 MFMA.
// A panel resident in LDS at half-K (restaged once -> 3 barriers/block total);
// B streamed global->register fragments (ping-pong, 1-kt prefetch, no barriers).
// Kernel sum via exp square-chain: x=2^(-l2*c4); sum = x+x^2+x^4+x^8+x^16.
// Upper-triangle tiles only (tj >= ti); block partial -> psum (deterministic).
__global__ __launch_bounds__(256, 2)
void k_mmd(const short* __restrict__ bfall, const float* __restrict__ sq,
           const float* __restrict__ cvals, double* __restrict__ psum) {
    __shared__ short As[BM * 256];   // 64 KB: 128 rows x 256 cols (half of K)
    __shared__ float wred[4];

    // T1: XCD-aware bijective swizzle (NBLK = 8*260), then triangular decode
    int bid = blockIdx.x;
    int swz = (bid & 7) * (NBLK / 8) + (bid >> 3);
    int rem = swz;
    int ti = 0;
    while (rem >= NT - ti) { rem -= NT - ti; ++ti; }
    int tj = ti + rem;

    const int t  = threadIdx.x;
    const int w  = t >> 6;       // wave 0..3
    const int l  = t & 63;
    const int wr = w >> 1, wc = w & 1;
    const int lr = l & 15;       // fragment row/col lane
    const int lk = l >> 4;       // 0..3 k-group

    const int rowA0 = ti * BM, rowB0 = tj * BM;
    const short* gA = bfall + (size_t)rowA0 * NCOLS;
    const short* gB = bfall + (size_t)rowB0 * NCOLS;

    // stage A half h (cols h*256 .. h*256+255) into As, swizzled source:
    // LDS chunk (row, slot) holds global chunk (row, slot ^ (row&7)), slot in [0,32)
    #define STAGEA(h)                                                              \
        _Pragma("unroll")                                                          \
        for (int i = 0; i < 16; ++i) {                                             \
            int q    = i * 256 + t;                                                \
            int row  = q >> 5;                                                     \
            int slot = q & 31;                                                     \
            int ss   = slot ^ (row & 7);                                           \
            const short* ga = gA + (size_t)row * NCOLS + (h) * 256 + ss * 8;       \
            __builtin_amdgcn_global_load_lds((guint*)ga, (luint*)(As + (size_t)q * 8), 16, 0, 0); \
        }

    // load the 8 B-fragments of K-step ktv into named regs (static indices)
    #define BLOAD(dst, ktv)                                                        \
        _Pragma("unroll")                                                          \
        for (int kk = 0; kk < 2; ++kk)                                             \
            _Pragma("unroll")                                                      \
            for (int n = 0; n < 4; ++n)                                            \
                dst[kk][n] = *(const s16x8*)(gB + (size_t)(wc*64 + n*16 + lr) * NCOLS \
                                             + (ktv) * 64 + (kk*4 + lk) * 8);

    // compute one K-step: local kt index ktl in [0,4) within current A half
    #define COMPUTE(ktl, bf)                                                       \
        _Pragma("unroll")                                                          \
        for (int kk = 0; kk < 2; ++kk) {                                           \
            s16x8 af[4];                                                           \
            int slotl = (ktl) * 8 + kk * 4 + lk;                                   \
            _Pragma("unroll")                                                      \
            for (int m = 0; m < 4; ++m) {                                          \
                int row = wr * 64 + m * 16 + lr;                                   \
                int ssl = slotl ^ (row & 7);                                       \
                af[m] = ((const s16x8*)As)[row * 32 + ssl];                        \
            }                                                                      \
            _Pragma("unroll")                                                      \
            for (int m = 0; m < 4; ++m)                                            \
                _Pragma("unroll")                                                  \
                for (int n = 0; n < 4; ++n)                                        \
                    acc[m][n] = __builtin_amdgcn_mfma_f32_16x16x32_bf16(           \
                        af[m], bf[kk][n], acc[m][n], 0, 0, 0);                     \
        }

    f32x4 acc[4][4] = {};
    s16x8 bfP[2][4], bfQ[2][4];

    // hoist epilogue operands
    float sqa[4][4], sqb[4];
    #pragma unroll
    for (int m = 0; m < 4; ++m)
        #pragma unroll
        for (int r = 0; r < 4; ++r)
            sqa[m][r] = sq[rowA0 + wr * 64 + m * 16 + lk * 4 + r];
    #pragma unroll
    for (int n = 0; n < 4; ++n)
        sqb[n] = sq[rowB0 + wc * 64 + n * 16 + lr];
    float c4 = cvals[4];

    STAGEA(0);
    BLOAD(bfP, 0);
    __syncthreads();                 // A half-0 (and bfP) ready

    BLOAD(bfQ, 1); COMPUTE(0, bfP);  // kt 0
    BLOAD(bfP, 2); COMPUTE(1, bfQ);  // kt 1
    BLOAD(bfQ, 3); COMPUTE(2, bfP);  // kt 2
    BLOAD(bfP, 4); COMPUTE(3, bfQ);  // kt 3

    __syncthreads();                 // all reads of A half-0 done
    STAGEA(1);
    __syncthreads();                 // A half-1 ready

    BLOAD(bfQ, 5); COMPUTE(0, bfP);  // kt 4
    BLOAD(bfP, 6); COMPUTE(1, bfQ);  // kt 5
    BLOAD(bfQ, 7); COMPUTE(2, bfP);  // kt 6
    COMPUTE(3, bfQ);                 // kt 7

    #undef STAGEA
    #undef BLOAD
    #undef COMPUTE

    // ---------- epilogue: l2 -> exp square-chain -> signed/weighted sum ----------
    const bool diag = (ti == tj);
    const float sgn = ((rowA0 < BHALF) == (rowB0 < BHALF)) ? 1.f : -1.f;
    float local = 0.f;
    #pragma unroll
    for (int m = 0; m < 4; ++m)
        #pragma unroll
        for (int n = 0; n < 4; ++n)
            #pragma unroll
            for (int r = 0; r < 4; ++r) {
                float d  = acc[m][n][r];
                float l2 = sqa[m][r] + sqb[n] - 2.f * d;
                // e_k = exp(-l2/(bw*2^k)) = x^(2^(4-k)), x = 2^(-l2*c4)
                float x  = exp2f(-l2 * c4);
                float x2 = x * x;
                float x4 = x2 * x2;
                float x8 = x4 * x4;
                float e  = x + x2 + x4 + x8 + x8 * x8;
                if (diag) {
                    int gi = rowA0 + wr * 64 + m * 16 + lk * 4 + r;
                    int gj = rowB0 + wc * 64 + n * 16 + lr;
                    float wgt = (gj > gi) ? 2.f : ((gj == gi) ? 1.f : 0.f);
                    local += wgt * e;
                } else {
                    local += e;
                }
            }
    if (!diag) local *= 2.f * sgn;   // diagonal tiles always sgn=+1

    #pragma unroll
    for (int o = 32; o > 0; o >>= 1) local += __shfl_down(local, o);
    if (l == 0) wred[w] = local;
    __syncthreads();
    if (t == 0) {
        psum[blockIdx.x] = (double)(wred[0] + wred[1] + wred[2] + wred[3]);
    }
}

// fixed-order final reduction over NBLK partials -> loss
__global__ void k_final(const double* __restrict__ psum, float* __restrict__ out) {
    __shared__ double red[256];
    int t = threadIdx.x;
    double a = 0.0;
    for (int i = t; i < NBLK; i += 256) a += psum[i];
    red[t] = a; __syncthreads();
    for (int o = 128; o > 0; o >>= 1) { if (t < o) red[t] += red[t + o]; __syncthreads(); }
    if (t == 0) out[0] = (float)(red[0] * (1.0 / ((double)BHALF * (double)BHALF)));
}

// ---------- launch ----------
extern "C" void kernel_launch(void* const* d_in, const int* in_sizes, int n_in,
                              void* d_out, int out_size, void* d_ws, size_t ws_size,
                              hipStream_t stream) {
    (void)in_sizes; (void)n_in; (void)out_size; (void)ws_size;
    const float* src = (const float*)d_in[0];
    const float* tgt = (const float*)d_in[1];
    float* out = (float*)d_out;
    char* ws = (char*)d_ws;
    // layout (all offsets 16B-aligned; every consumed word is rewritten each call):
    short*  bfall  = (short*) (ws);                      // 8192*512*2 = 8388608 B
    float*  sq     = (float*) (ws + 8388608);            // 8192*4 = 32768 B
    float*  cspart = (float*) (ws + 8388608 + 32768);    // 256*512*4 = 524288 B
    float*  cvals  = (float*) (ws + 8388608 + 32768 + 524288);        // 20 B
    double* psum   = (double*)(ws + 8388608 + 32768 + 524288 + 32);   // 2080*8 = 16640 B

    k_conv  <<<CSPART, 256, 0, stream>>>(src, tgt, bfall, sq, cspart);
    k_bw    <<<1, 512, 0, stream>>>(sq, cspart, cvals);
    k_mmd   <<<NBLK, 256, 0, stream>>>(bfall, sq, cvals, psum);
    k_final <<<1, 256, 0, stream>>>(psum, out);
}

// Round 6
// 116.993 us; speedup vs baseline: 1.0254x; 1.0254x over previous
//
#include <hip/hip_runtime.h>
#include <math.h>

typedef float f32x4 __attribute__((ext_vector_type(4)));
typedef short s16x8 __attribute__((ext_vector_type(8)));

#define NROWS 8192
#define NCOLS 512
#define BHALF 4096
#define NT    64       // 8192 / 128 tiles per dim
#define BM    128
#define BK    32
#define NKT   (NCOLS / BK)          // 16 K-steps
#define NBLK  (NT * (NT + 1) / 2)   // 2080 triangular tiles (2080 % 8 == 0)
#define CSPART 256                   // colsum partial blocks

typedef __attribute__((address_space(1))) const unsigned int guint;
typedef __attribute__((address_space(3))) unsigned int luint;

// ---------- helpers ----------
__device__ __forceinline__ unsigned short f2bf(float f) {
    // RNE float -> bf16 (inputs are finite normals; no NaN handling needed)
    unsigned u = __builtin_bit_cast(unsigned, f);
    u += 0x7FFFu + ((u >> 16) & 1u);
    return (unsigned short)(u >> 16);
}

// ---------- fused conversion + row-sq + colsum partials ----------
// 256 blocks x 256 threads; block covers 32 rows (8 rows per wave).
// Deterministic: all reductions fixed-order, no atomics.
__global__ void k_conv(const float* __restrict__ src, const float* __restrict__ tgt,
                       short* __restrict__ bfall, float* __restrict__ sq,
                       float* __restrict__ cspart) {
    __shared__ float colp[4][NCOLS];
    int t = threadIdx.x, w = t >> 6, l = t & 63;
    int r0 = blockIdx.x * 32 + w * 8;
    float c0x=0.f,c0y=0.f,c0z=0.f,c0w=0.f, c1x=0.f,c1y=0.f,c1z=0.f,c1w=0.f;
    #pragma unroll
    for (int r = 0; r < 8; ++r) {
        int row = r0 + r;
        const float* base = (row < BHALF) ? (src + (size_t)row * NCOLS)
                                          : (tgt + (size_t)(row - BHALF) * NCOLS);
        float4 a = ((const float4*)base)[2 * l];
        float4 b = ((const float4*)base)[2 * l + 1];
        s16x8 v;
        v[0] = (short)f2bf(a.x); v[1] = (short)f2bf(a.y);
        v[2] = (short)f2bf(a.z); v[3] = (short)f2bf(a.w);
        v[4] = (short)f2bf(b.x); v[5] = (short)f2bf(b.y);
        v[6] = (short)f2bf(b.z); v[7] = (short)f2bf(b.w);
        ((s16x8*)(bfall + (size_t)row * NCOLS))[l] = v;
        float s = a.x*a.x + a.y*a.y + a.z*a.z + a.w*a.w
                + b.x*b.x + b.y*b.y + b.z*b.z + b.w*b.w;
        #pragma unroll
        for (int o = 32; o > 0; o >>= 1) s += __shfl_down(s, o);
        if (l == 0) sq[row] = s;
        c0x += a.x; c0y += a.y; c0z += a.z; c0w += a.w;
        c1x += b.x; c1y += b.y; c1z += b.z; c1w += b.w;
    }
    colp[w][l*8+0] = c0x; colp[w][l*8+1] = c0y; colp[w][l*8+2] = c0z; colp[w][l*8+3] = c0w;
    colp[w][l*8+4] = c1x; colp[w][l*8+5] = c1y; colp[w][l*8+6] = c1z; colp[w][l*8+7] = c1w;
    __syncthreads();
    float s0 = colp[0][t] + colp[1][t] + colp[2][t] + colp[3][t];
    float s1 = colp[0][t+256] + colp[1][t+256] + colp[2][t+256] + colp[3][t+256];
    cspart[(size_t)blockIdx.x * NCOLS + t]       = s0;
    cspart[(size_t)blockIdx.x * NCOLS + t + 256] = s1;
}

// bandwidth from analytic sum(l2) = 2n*T - 2*||colsum||^2 ; store log2(e)/bw_k
// fully fixed-order -> deterministic
__global__ void k_bw(const float* __restrict__ sq, const float* __restrict__ colsum_part,
                     float* __restrict__ cvals) {
    __shared__ double red[512];
    __shared__ double sT;
    int t = threadIdx.x;
    double acc = 0.0;
    for (int i = t; i < NROWS; i += 512) acc += (double)sq[i];
    red[t] = acc; __syncthreads();
    for (int o = 256; o > 0; o >>= 1) { if (t < o) red[t] += red[t + o]; __syncthreads(); }
    if (t == 0) sT = red[0];
    __syncthreads();
    double c = 0.0;
    for (int p = 0; p < CSPART; ++p) c += (double)colsum_part[(size_t)p * NCOLS + t];
    red[t] = c * c; __syncthreads();
    for (int o = 256; o > 0; o >>= 1) { if (t < o) red[t] += red[t + o]; __syncthreads(); }
    if (t == 0) {
        double G = red[0];
        double sum_l2 = 2.0 * (double)NROWS * sT - 2.0 * G;
        double denom = (double)NROWS * (double)NROWS - (double)NROWS;
        double bw = sum_l2 / denom / 4.0;   // KERNEL_MUL^(KERNEL_NUM/2) = 4
        const double L2E = 1.4426950408889634;
        double b = bw;
        #pragma unroll
        for (int k = 0; k < 5; ++k) { cvals[k] = (float)(L2E / b); b *= 2.0; }
    }
}

// ---------- main fused MMD kernel ----------
// 128x128 tile per block, 4 waves (2x2), wave tile 64x64 via 4x4 of 16x16x32 MFMA.
// BK=32, double-buffered LDS (33 KB total -> 4 blocks/CU); stage(kt+1) issued
// before compute(kt); one barrier per K-step. Both tiles via global_load_lds
// (linear LDS dest, pre-swizzled global source). Swizzle ss = slot^((row>>1)&3):
// conflict-free for 64B-stride rows (bank = 16*(row&1) + 4*ss covers all 32 banks
// per 8 consecutive rows). Kernel sum via exp square-chain. Triangular tiles;
// block partial -> psum (deterministic, no atomics).
__global__ __launch_bounds__(256, 4)
void k_mmd(const short* __restrict__ bfall, const float* __restrict__ sq,
           const float* __restrict__ cvals, double* __restrict__ psum) {
    __shared__ short As[2][BM * BK];   // 2 x 8 KB
    __shared__ short Bs[2][BM * BK];   // 2 x 8 KB
    __shared__ float wred[4];

    // T1: XCD-aware bijective swizzle (NBLK = 8*260), then triangular decode
    int bid = blockIdx.x;
    int swz = (bid & 7) * (NBLK / 8) + (bid >> 3);
    int rem = swz;
    int ti = 0;
    while (rem >= NT - ti) { rem -= NT - ti; ++ti; }
    int tj = ti + rem;

    const int t  = threadIdx.x;
    const int w  = t >> 6;       // wave 0..3
    const int l  = t & 63;
    const int wr = w >> 1, wc = w & 1;
    const int lr = l & 15;       // fragment row/col lane
    const int lk = l >> 4;       // 0..3 k-group (8 bf16 = 1 slot each)

    const int rowA0 = ti * BM, rowB0 = tj * BM;
    const short* gA = bfall + (size_t)rowA0 * NCOLS;
    const short* gB = bfall + (size_t)rowB0 * NCOLS;

    // stage tile kt into buffer bsel: 512 chunks each for A and B, 2 per thread.
    // LDS chunk (row, slot) holds global chunk (row, slot ^ ((row>>1)&3)).
    #define STAGE(bsel, kt)                                                        \
        _Pragma("unroll")                                                          \
        for (int i = 0; i < 2; ++i) {                                              \
            int q    = i * 256 + t;                                                \
            int row  = q >> 2;                                                     \
            int slot = q & 3;                                                      \
            int ss   = slot ^ ((row >> 1) & 3);                                    \
            const short* ga = gA + (size_t)row * NCOLS + (kt) * BK + ss * 8;       \
            const short* gb = gB + (size_t)row * NCOLS + (kt) * BK + ss * 8;       \
            __builtin_amdgcn_global_load_lds((guint*)ga,                           \
                (luint*)(&As[bsel][(size_t)q * 8]), 16, 0, 0);                     \
            __builtin_amdgcn_global_load_lds((guint*)gb,                           \
                (luint*)(&Bs[bsel][(size_t)q * 8]), 16, 0, 0);                     \
        }

    // compute one K-step from buffer bsel: 8 ds_read_b128 + 16 MFMA per wave
    #define COMPUTE(bsel)                                                          \
        {                                                                          \
            s16x8 af[4], bf[4];                                                    \
            _Pragma("unroll")                                                      \
            for (int m = 0; m < 4; ++m) {                                          \
                int row = wr * 64 + m * 16 + lr;                                   \
                int ssl = lk ^ ((row >> 1) & 3);                                   \
                af[m] = ((const s16x8*)As[bsel])[row * 4 + ssl];                    \
            }                                                                      \
            _Pragma("unroll")                                                      \
            for (int n = 0; n < 4; ++n) {                                          \
                int row = wc * 64 + n * 16 + lr;                                   \
                int ssl = lk ^ ((row >> 1) & 3);                                   \
                bf[n] = ((const s16x8*)Bs[bsel])[row * 4 + ssl];                    \
            }                                                                      \
            _Pragma("unroll")                                                      \
            for (int m = 0; m < 4; ++m)                                            \
                _Pragma("unroll")                                                  \
                for (int n = 0; n < 4; ++n)                                        \
                    acc[m][n] = __builtin_amdgcn_mfma_f32_16x16x32_bf16(           \
                        af[m], bf[n], acc[m][n], 0, 0, 0);                         \
        }

    f32x4 acc[4][4] = {};

    // hoist epilogue operands
    float sqa[4][4], sqb[4];
    #pragma unroll
    for (int m = 0; m < 4; ++m)
        #pragma unroll
        for (int r = 0; r < 4; ++r)
            sqa[m][r] = sq[rowA0 + wr * 64 + m * 16 + lk * 4 + r];
    #pragma unroll
    for (int n = 0; n < 4; ++n)
        sqb[n] = sq[rowB0 + wc * 64 + n * 16 + lr];
    float c4 = cvals[4];

    STAGE(0, 0);
    __syncthreads();   // tile 0 ready (implicit vmcnt drain)

    int cur = 0;
    #pragma unroll 4
    for (int kt = 0; kt < NKT; ++kt) {
        if (kt + 1 < NKT) { STAGE(cur ^ 1, kt + 1); }   // prefetch next tile
        COMPUTE(cur);
        __syncthreads();   // reads of 'cur' done; prefetch drained -> next ready
        cur ^= 1;
    }
    #undef STAGE
    #undef COMPUTE

    // ---------- epilogue: l2 -> exp square-chain -> signed/weighted sum ----------
    const bool diag = (ti == tj);
    const float sgn = ((rowA0 < BHALF) == (rowB0 < BHALF)) ? 1.f : -1.f;
    float local = 0.f;
    #pragma unroll
    for (int m = 0; m < 4; ++m)
        #pragma unroll
        for (int n = 0; n < 4; ++n)
            #pragma unroll
            for (int r = 0; r < 4; ++r) {
                float d  = acc[m][n][r];
                float l2 = sqa[m][r] + sqb[n] - 2.f * d;
                // e_k = exp(-l2/(bw*2^k)) = x^(2^(4-k)), x = 2^(-l2*c4)
                float x  = exp2f(-l2 * c4);
                float x2 = x * x;
                float x4 = x2 * x2;
                float x8 = x4 * x4;
                float e  = x + x2 + x4 + x8 + x8 * x8;
                if (diag) {
                    int gi = rowA0 + wr * 64 + m * 16 + lk * 4 + r;
                    int gj = rowB0 + wc * 64 + n * 16 + lr;
                    float wgt = (gj > gi) ? 2.f : ((gj == gi) ? 1.f : 0.f);
                    local += wgt * e;
                } else {
                    local += e;
                }
            }
    if (!diag) local *= 2.f * sgn;   // diagonal tiles always sgn=+1

    #pragma unroll
    for (int o = 32; o > 0; o >>= 1) local += __shfl_down(local, o);
    if (l == 0) wred[w] = local;
    __syncthreads();
    if (t == 0) {
        psum[blockIdx.x] = (double)(wred[0] + wred[1] + wred[2] + wred[3]);
    }
}

// fixed-order final reduction over NBLK partials -> loss
__global__ void k_final(const double* __restrict__ psum, float* __restrict__ out) {
    __shared__ double red[256];
    int t = threadIdx.x;
    double a = 0.0;
    for (int i = t; i < NBLK; i += 256) a += psum[i];
    red[t] = a; __syncthreads();
    for (int o = 128; o > 0; o >>= 1) { if (t < o) red[t] += red[t + o]; __syncthreads(); }
    if (t == 0) out[0] = (float)(red[0] * (1.0 / ((double)BHALF * (double)BHALF)));
}

// ---------- launch ----------
extern "C" void kernel_launch(void* const* d_in, const int* in_sizes, int n_in,
                              void* d_out, int out_size, void* d_ws, size_t ws_size,
                              hipStream_t stream) {
    (void)in_sizes; (void)n_in; (void)out_size; (void)ws_size;
    const float* src = (const float*)d_in[0];
    const float* tgt = (const float*)d_in[1];
    float* out = (float*)d_out;
    char* ws = (char*)d_ws;
    // layout (all offsets 16B-aligned; every consumed word is rewritten each call):
    short*  bfall  = (short*) (ws);                      // 8192*512*2 = 8388608 B
    float*  sq     = (float*) (ws + 8388608);            // 8192*4 = 32768 B
    float*  cspart = (float*) (ws + 8388608 + 32768);    // 256*512*4 = 524288 B
    float*  cvals  = (float*) (ws + 8388608 + 32768 + 524288);        // 20 B
    double* psum   = (double*)(ws + 8388608 + 32768 + 524288 + 32);   // 2080*8 = 16640 B

    k_conv  <<<CSPART, 256, 0, stream>>>(src, tgt, bfall, sq, cspart);
    k_bw    <<<1, 512, 0, stream>>>(sq, cspart, cvals);
    k_mmd   <<<NBLK, 256, 0, stream>>>(bfall, sq, cvals, psum);
    k_final <<<1, 256, 0, stream>>>(psum, out);
}

// Round 7
// 86.114 us; speedup vs baseline: 1.3932x; 1.3586x over previous
//
#include <hip/hip_runtime.h>
#include <math.h>

typedef float f32x4 __attribute__((ext_vector_type(4)));
typedef short s16x8 __attribute__((ext_vector_type(8)));

#define NROWS 8192
#define NCOLS 512
#define BHALF 4096
#define NT    64       // 8192 / 128 tiles per dim
#define BM    128
#define BK    32
#define NKT   (NCOLS / BK)          // 16 K-steps
#define NBLK  (NT * (NT + 1) / 2)   // 2080 triangular tiles (2080 % 8 == 0)
#define CSPART 256                   // colsum partial blocks

typedef __attribute__((address_space(1))) const unsigned int guint;
typedef __attribute__((address_space(3))) unsigned int luint;

// ---------- helpers ----------
__device__ __forceinline__ unsigned short f2bf(float f) {
    // RNE float -> bf16 (inputs are finite normals; no NaN handling needed)
    unsigned u = __builtin_bit_cast(unsigned, f);
    u += 0x7FFFu + ((u >> 16) & 1u);
    return (unsigned short)(u >> 16);
}

// ---------- fused conversion + row-sq + colsum partials ----------
// 256 blocks x 256 threads; block covers 32 rows (8 rows per wave).
// Deterministic: all reductions fixed-order, no atomics.
__global__ void k_conv(const float* __restrict__ src, const float* __restrict__ tgt,
                       short* __restrict__ bfall, float* __restrict__ sq,
                       float* __restrict__ cspart) {
    __shared__ float colp[4][NCOLS];
    int t = threadIdx.x, w = t >> 6, l = t & 63;
    int r0 = blockIdx.x * 32 + w * 8;
    float c0x=0.f,c0y=0.f,c0z=0.f,c0w=0.f, c1x=0.f,c1y=0.f,c1z=0.f,c1w=0.f;
    #pragma unroll
    for (int r = 0; r < 8; ++r) {
        int row = r0 + r;
        const float* base = (row < BHALF) ? (src + (size_t)row * NCOLS)
                                          : (tgt + (size_t)(row - BHALF) * NCOLS);
        float4 a = ((const float4*)base)[2 * l];
        float4 b = ((const float4*)base)[2 * l + 1];
        s16x8 v;
        v[0] = (short)f2bf(a.x); v[1] = (short)f2bf(a.y);
        v[2] = (short)f2bf(a.z); v[3] = (short)f2bf(a.w);
        v[4] = (short)f2bf(b.x); v[5] = (short)f2bf(b.y);
        v[6] = (short)f2bf(b.z); v[7] = (short)f2bf(b.w);
        ((s16x8*)(bfall + (size_t)row * NCOLS))[l] = v;
        float s = a.x*a.x + a.y*a.y + a.z*a.z + a.w*a.w
                + b.x*b.x + b.y*b.y + b.z*b.z + b.w*b.w;
        #pragma unroll
        for (int o = 32; o > 0; o >>= 1) s += __shfl_down(s, o);
        if (l == 0) sq[row] = s;
        c0x += a.x; c0y += a.y; c0z += a.z; c0w += a.w;
        c1x += b.x; c1y += b.y; c1z += b.z; c1w += b.w;
    }
    colp[w][l*8+0] = c0x; colp[w][l*8+1] = c0y; colp[w][l*8+2] = c0z; colp[w][l*8+3] = c0w;
    colp[w][l*8+4] = c1x; colp[w][l*8+5] = c1y; colp[w][l*8+6] = c1z; colp[w][l*8+7] = c1w;
    __syncthreads();
    float s0 = colp[0][t] + colp[1][t] + colp[2][t] + colp[3][t];
    float s1 = colp[0][t+256] + colp[1][t+256] + colp[2][t+256] + colp[3][t+256];
    cspart[(size_t)blockIdx.x * NCOLS + t]       = s0;
    cspart[(size_t)blockIdx.x * NCOLS + t + 256] = s1;
}

// bandwidth from analytic sum(l2) = 2n*T - 2*||colsum||^2 ; store log2(e)/bw_k.
// 1024 threads, independent accumulator chains, fixed-order -> deterministic.
__global__ void k_bw(const float* __restrict__ sq, const float* __restrict__ cspart,
                     float* __restrict__ cvals) {
    __shared__ double red[1024];
    int t = threadIdx.x;
    // phase 1: sum of sq (8 independent loads per thread)
    double a = 0.0;
    #pragma unroll
    for (int i = 0; i < 8; ++i) a += (double)sq[t + i * 1024];
    red[t] = a; __syncthreads();
    for (int o = 512; o > 0; o >>= 1) { if (t < o) red[t] += red[t + o]; __syncthreads(); }
    double sT = red[0];
    __syncthreads();
    // phase 2: colsum over 256 partials; thread t: col c = t&511, half h = t>>9
    int c = t & 511, h = t >> 9;
    double d0 = 0.0, d1 = 0.0, d2 = 0.0, d3 = 0.0;
    int p0 = h * 128;
    #pragma unroll 8
    for (int p = 0; p < 128; p += 4) {
        d0 += (double)cspart[(size_t)(p0 + p + 0) * NCOLS + c];
        d1 += (double)cspart[(size_t)(p0 + p + 1) * NCOLS + c];
        d2 += (double)cspart[(size_t)(p0 + p + 2) * NCOLS + c];
        d3 += (double)cspart[(size_t)(p0 + p + 3) * NCOLS + c];
    }
    red[t] = (d0 + d1) + (d2 + d3);
    __syncthreads();
    double v = 0.0;
    if (t < 512) { double cs = red[t] + red[t + 512]; v = cs * cs; }
    __syncthreads();
    red[t] = v; __syncthreads();
    for (int o = 512; o > 0; o >>= 1) { if (t < o) red[t] += red[t + o]; __syncthreads(); }
    if (t == 0) {
        double G = red[0];
        double sum_l2 = 2.0 * (double)NROWS * sT - 2.0 * G;
        double denom = (double)NROWS * (double)NROWS - (double)NROWS;
        double bw = sum_l2 / denom / 4.0;   // KERNEL_MUL^(KERNEL_NUM/2) = 4
        const double L2E = 1.4426950408889634;
        double b = bw;
        #pragma unroll
        for (int k = 0; k < 5; ++k) { cvals[k] = (float)(L2E / b); b *= 2.0; }
    }
}

// ---------- main fused MMD kernel ----------
// 128x128 tile per block, 4 waves (2x2), wave tile 64x64 via 4x4 of 16x16x32 MFMA.
// BK=32, THREE LDS buffers (48 KB), 2-tiles-ahead prefetch with COUNTED vmcnt
// (s_waitcnt vmcnt(4) + raw s_barrier per K-step; never drained to 0 mid-loop).
// Both tiles via global_load_lds (linear LDS dest, pre-swizzled global source,
// swizzle ss = slot^((row>>1)&3), conflict-free: bank = 16*(row&1)+4*ss).
// launch_bounds(256,3): ~170-reg budget -> no spill (R6's (256,4)=128 spilled).
// All epilogue global loads AFTER the K-loop (keeps vmcnt counts exact).
// Kernel sum via exp square-chain. Triangular tiles; psum (deterministic).
__global__ __launch_bounds__(256, 3)
void k_mmd(const short* __restrict__ bfall, const float* __restrict__ sq,
           const float* __restrict__ cvals, double* __restrict__ psum) {
    __shared__ short As[3][BM * BK];   // 3 x 8 KB
    __shared__ short Bs[3][BM * BK];   // 3 x 8 KB
    __shared__ float wred[4];

    // T1: XCD-aware bijective swizzle (NBLK = 8*260), then triangular decode
    int bid = blockIdx.x;
    int swz = (bid & 7) * (NBLK / 8) + (bid >> 3);
    int rem = swz;
    int ti = 0;
    while (rem >= NT - ti) { rem -= NT - ti; ++ti; }
    int tj = ti + rem;

    const int t  = threadIdx.x;
    const int w  = t >> 6;       // wave 0..3
    const int l  = t & 63;
    const int wr = w >> 1, wc = w & 1;
    const int lr = l & 15;       // fragment row/col lane
    const int lk = l >> 4;       // 0..3 k-group (8 bf16 = 1 slot each)

    const int rowA0 = ti * BM, rowB0 = tj * BM;
    const short* gA = bfall + (size_t)rowA0 * NCOLS;
    const short* gB = bfall + (size_t)rowB0 * NCOLS;

    // stage tile kt into buffer bsel: per thread 2 A-chunks + 2 B-chunks (16 B).
    // LDS chunk (row, slot) holds global chunk (row, slot ^ ((row>>1)&3)).
    // 4 global_load_lds instructions per wave per STAGE -> vmcnt +4.
    #define STAGE(bsel, kt)                                                        \
        _Pragma("unroll")                                                          \
        for (int i = 0; i < 2; ++i) {                                              \
            int q    = i * 256 + t;                                                \
            int row  = q >> 2;                                                     \
            int slot = q & 3;                                                      \
            int ss   = slot ^ ((row >> 1) & 3);                                    \
            const short* ga = gA + (size_t)row * NCOLS + (kt) * BK + ss * 8;       \
            const short* gb = gB + (size_t)row * NCOLS + (kt) * BK + ss * 8;       \
            __builtin_amdgcn_global_load_lds((guint*)ga,                           \
                (luint*)(&As[bsel][(size_t)q * 8]), 16, 0, 0);                     \
            __builtin_amdgcn_global_load_lds((guint*)gb,                           \
                (luint*)(&Bs[bsel][(size_t)q * 8]), 16, 0, 0);                     \
        }

    // compute one K-step from buffer bsel: 8 ds_read_b128 + 16 MFMA per wave
    #define COMPUTE(bsel)                                                          \
        {                                                                          \
            s16x8 af[4], bf[4];                                                    \
            _Pragma("unroll")                                                      \
            for (int m = 0; m < 4; ++m) {                                          \
                int row = wr * 64 + m * 16 + lr;                                   \
                int ssl = lk ^ ((row >> 1) & 3);                                   \
                af[m] = ((const s16x8*)As[bsel])[row * 4 + ssl];                   \
            }                                                                      \
            _Pragma("unroll")                                                      \
            for (int n = 0; n < 4; ++n) {                                          \
                int row = wc * 64 + n * 16 + lr;                                   \
                int ssl = lk ^ ((row >> 1) & 3);                                   \
                bf[n] = ((const s16x8*)Bs[bsel])[row * 4 + ssl];                   \
            }                                                                      \
            _Pragma("unroll")                                                      \
            for (int m = 0; m < 4; ++m)                                            \
                _Pragma("unroll")                                                  \
                for (int n = 0; n < 4; ++n)                                        \
                    acc[m][n] = __builtin_amdgcn_mfma_f32_16x16x32_bf16(           \
                        af[m], bf[n], acc[m][n], 0, 0, 0);                         \
        }

    // one pipeline step: wait own stage(kt) landed (vmcnt<=vm: tiles kt+1,kt+2
    // may stay in flight), barrier (all waves' stage(kt) landed + all waves
    // done reading buffer (kt+2)%3 == (kt-1)%3), prefetch kt+2, compute kt.
    #define STEP(kt, vm)                                                           \
        asm volatile("s_waitcnt vmcnt(" #vm ")" ::: "memory");                     \
        __builtin_amdgcn_s_barrier();                                              \
        asm volatile("" ::: "memory");                                             \
        if ((kt) + 2 < NKT) { STAGE(((kt) + 2) % 3, (kt) + 2); }                   \
        COMPUTE((kt) % 3);

    f32x4 acc[4][4] = {};

    STAGE(0, 0);
    STAGE(1, 1);        // 8 loads in flight

    STEP(0, 4)  STEP(1, 4)  STEP(2, 4)  STEP(3, 4)
    STEP(4, 4)  STEP(5, 4)  STEP(6, 4)  STEP(7, 4)
    STEP(8, 4)  STEP(9, 4)  STEP(10, 4) STEP(11, 4)
    STEP(12, 4) STEP(13, 4) STEP(14, 4) STEP(15, 0)

    #undef STAGE
    #undef COMPUTE
    #undef STEP

    // ---------- epilogue: l2 -> exp square-chain -> signed/weighted sum ----------
    // (global loads kept AFTER the K-loop so they don't perturb vmcnt counts)
    float sqa[4][4], sqb[4];
    #pragma unroll
    for (int m = 0; m < 4; ++m)
        #pragma unroll
        for (int r = 0; r < 4; ++r)
            sqa[m][r] = sq[rowA0 + wr * 64 + m * 16 + lk * 4 + r];
    #pragma unroll
    for (int n = 0; n < 4; ++n)
        sqb[n] = sq[rowB0 + wc * 64 + n * 16 + lr];
    float c4 = cvals[4];

    const bool diag = (ti == tj);
    const float sgn = ((rowA0 < BHALF) == (rowB0 < BHALF)) ? 1.f : -1.f;
    float local = 0.f;
    #pragma unroll
    for (int m = 0; m < 4; ++m)
        #pragma unroll
        for (int n = 0; n < 4; ++n)
            #pragma unroll
            for (int r = 0; r < 4; ++r) {
                float d  = acc[m][n][r];
                float l2 = sqa[m][r] + sqb[n] - 2.f * d;
                // e_k = exp(-l2/(bw*2^k)) = x^(2^(4-k)), x = 2^(-l2*c4)
                float x  = exp2f(-l2 * c4);
                float x2 = x * x;
                float x4 = x2 * x2;
                float x8 = x4 * x4;
                float e  = x + x2 + x4 + x8 + x8 * x8;
                if (diag) {
                    int gi = rowA0 + wr * 64 + m * 16 + lk * 4 + r;
                    int gj = rowB0 + wc * 64 + n * 16 + lr;
                    float wgt = (gj > gi) ? 2.f : ((gj == gi) ? 1.f : 0.f);
                    local += wgt * e;
                } else {
                    local += e;
                }
            }
    if (!diag) local *= 2.f * sgn;   // diagonal tiles always sgn=+1

    #pragma unroll
    for (int o = 32; o > 0; o >>= 1) local += __shfl_down(local, o);
    if (l == 0) wred[w] = local;
    __syncthreads();
    if (t == 0) {
        psum[blockIdx.x] = (double)(wred[0] + wred[1] + wred[2] + wred[3]);
    }
}

// fixed-order final reduction over NBLK partials -> loss
__global__ void k_final(const double* __restrict__ psum, float* __restrict__ out) {
    __shared__ double red[256];
    int t = threadIdx.x;
    double a = 0.0;
    for (int i = t; i < NBLK; i += 256) a += psum[i];
    red[t] = a; __syncthreads();
    for (int o = 128; o > 0; o >>= 1) { if (t < o) red[t] += red[t + o]; __syncthreads(); }
    if (t == 0) out[0] = (float)(red[0] * (1.0 / ((double)BHALF * (double)BHALF)));
}

// ---------- launch ----------
extern "C" void kernel_launch(void* const* d_in, const int* in_sizes, int n_in,
                              void* d_out, int out_size, void* d_ws, size_t ws_size,
                              hipStream_t stream) {
    (void)in_sizes; (void)n_in; (void)out_size; (void)ws_size;
    const float* src = (const float*)d_in[0];
    const float* tgt = (const float*)d_in[1];
    float* out = (float*)d_out;
    char* ws = (char*)d_ws;
    // layout (all offsets 16B-aligned; every consumed word is rewritten each call):
    short*  bfall  = (short*) (ws);                      // 8192*512*2 = 8388608 B
    float*  sq     = (float*) (ws + 8388608);            // 8192*4 = 32768 B
    float*  cspart = (float*) (ws + 8388608 + 32768);    // 256*512*4 = 524288 B
    float*  cvals  = (float*) (ws + 8388608 + 32768 + 524288);        // 20 B
    double* psum   = (double*)(ws + 8388608 + 32768 + 524288 + 32);   // 2080*8 = 16640 B

    k_conv  <<<CSPART, 256, 0, stream>>>(src, tgt, bfall, sq, cspart);
    k_bw    <<<1, 1024, 0, stream>>>(sq, cspart, cvals);
    k_mmd   <<<NBLK, 256, 0, stream>>>(bfall, sq, cvals, psum);
    k_final <<<1, 256, 0, stream>>>(psum, out);
}

// Round 9
// 82.891 us; speedup vs baseline: 1.4473x; 1.0389x over previous
//
#include <hip/hip_runtime.h>
#include <math.h>

typedef float f32x4 __attribute__((ext_vector_type(4)));
typedef short s16x8 __attribute__((ext_vector_type(8)));

#define NROWS 8192
#define NCOLS 512
#define BHALF 4096
#define NT    64       // 8192 / 128 tiles per dim
#define BM    128
#define BK    32
#define NKT   (NCOLS / BK)          // 16 K-steps
#define NBLK  (NT * (NT + 1) / 2)   // 2080 triangular tiles (2080 % 8 == 0)
#define CSPART 256                   // colsum partial blocks

typedef __attribute__((address_space(1))) const unsigned int guint;
typedef __attribute__((address_space(3))) unsigned int luint;

// ---------- helpers ----------
__device__ __forceinline__ unsigned short f2bf(float f) {
    // RNE float -> bf16 (inputs are finite normals; no NaN handling needed)
    unsigned u = __builtin_bit_cast(unsigned, f);
    u += 0x7FFFu + ((u >> 16) & 1u);
    return (unsigned short)(u >> 16);
}

// ---------- fused conversion + row-sq + colsum partials ----------
// 256 blocks x 256 threads; block covers 32 rows (8 rows per wave).
// Deterministic: all reductions fixed-order, no atomics.
__global__ void k_conv(const float* __restrict__ src, const float* __restrict__ tgt,
                       short* __restrict__ bfall, float* __restrict__ sq,
                       float* __restrict__ cspart) {
    __shared__ float colp[4][NCOLS];
    int t = threadIdx.x, w = t >> 6, l = t & 63;
    int r0 = blockIdx.x * 32 + w * 8;
    float c0x=0.f,c0y=0.f,c0z=0.f,c0w=0.f, c1x=0.f,c1y=0.f,c1z=0.f,c1w=0.f;
    #pragma unroll
    for (int r = 0; r < 8; ++r) {
        int row = r0 + r;
        const float* base = (row < BHALF) ? (src + (size_t)row * NCOLS)
                                          : (tgt + (size_t)(row - BHALF) * NCOLS);
        float4 a = ((const float4*)base)[2 * l];
        float4 b = ((const float4*)base)[2 * l + 1];
        s16x8 v;
        v[0] = (short)f2bf(a.x); v[1] = (short)f2bf(a.y);
        v[2] = (short)f2bf(a.z); v[3] = (short)f2bf(a.w);
        v[4] = (short)f2bf(b.x); v[5] = (short)f2bf(b.y);
        v[6] = (short)f2bf(b.z); v[7] = (short)f2bf(b.w);
        ((s16x8*)(bfall + (size_t)row * NCOLS))[l] = v;
        float s = a.x*a.x + a.y*a.y + a.z*a.z + a.w*a.w
                + b.x*b.x + b.y*b.y + b.z*b.z + b.w*b.w;
        #pragma unroll
        for (int o = 32; o > 0; o >>= 1) s += __shfl_down(s, o);
        if (l == 0) sq[row] = s;
        c0x += a.x; c0y += a.y; c0z += a.z; c0w += a.w;
        c1x += b.x; c1y += b.y; c1z += b.z; c1w += b.w;
    }
    colp[w][l*8+0] = c0x; colp[w][l*8+1] = c0y; colp[w][l*8+2] = c0z; colp[w][l*8+3] = c0w;
    colp[w][l*8+4] = c1x; colp[w][l*8+5] = c1y; colp[w][l*8+6] = c1z; colp[w][l*8+7] = c1w;
    __syncthreads();
    float s0 = colp[0][t] + colp[1][t] + colp[2][t] + colp[3][t];
    float s1 = colp[0][t+256] + colp[1][t+256] + colp[2][t+256] + colp[3][t+256];
    cspart[(size_t)blockIdx.x * NCOLS + t]       = s0;
    cspart[(size_t)blockIdx.x * NCOLS + t + 256] = s1;
}

// bandwidth from analytic sum(l2) = 2n*T - 2*||colsum||^2 ; store log2(e)/bw_k.
// 1024 threads, independent accumulator chains, fixed-order -> deterministic.
__global__ void k_bw(const float* __restrict__ sq, const float* __restrict__ cspart,
                     float* __restrict__ cvals) {
    __shared__ double red[1024];
    int t = threadIdx.x;
    // phase 1: sum of sq (8 independent loads per thread)
    double a = 0.0;
    #pragma unroll
    for (int i = 0; i < 8; ++i) a += (double)sq[t + i * 1024];
    red[t] = a; __syncthreads();
    for (int o = 512; o > 0; o >>= 1) { if (t < o) red[t] += red[t + o]; __syncthreads(); }
    double sT = red[0];
    __syncthreads();
    // phase 2: colsum over 256 partials; thread t: col c = t&511, half h = t>>9
    int c = t & 511, h = t >> 9;
    double d0 = 0.0, d1 = 0.0, d2 = 0.0, d3 = 0.0;
    int p0 = h * 128;
    #pragma unroll 8
    for (int p = 0; p < 128; p += 4) {
        d0 += (double)cspart[(size_t)(p0 + p + 0) * NCOLS + c];
        d1 += (double)cspart[(size_t)(p0 + p + 1) * NCOLS + c];
        d2 += (double)cspart[(size_t)(p0 + p + 2) * NCOLS + c];
        d3 += (double)cspart[(size_t)(p0 + p + 3) * NCOLS + c];
    }
    red[t] = (d0 + d1) + (d2 + d3);
    __syncthreads();
    double v = 0.0;
    if (t < 512) { double cs = red[t] + red[t + 512]; v = cs * cs; }
    __syncthreads();
    red[t] = v; __syncthreads();
    for (int o = 512; o > 0; o >>= 1) { if (t < o) red[t] += red[t + o]; __syncthreads(); }
    if (t == 0) {
        double G = red[0];
        double sum_l2 = 2.0 * (double)NROWS * sT - 2.0 * G;
        double denom = (double)NROWS * (double)NROWS - (double)NROWS;
        double bw = sum_l2 / denom / 4.0;   // KERNEL_MUL^(KERNEL_NUM/2) = 4
        const double L2E = 1.4426950408889634;
        double b = bw;
        #pragma unroll
        for (int k = 0; k < 5; ++k) { cvals[k] = (float)(L2E / b); b *= 2.0; }
    }
}

// ---------- main fused MMD kernel ----------
// R7 pipeline (3 LDS buffers, counted vmcnt(4), vmcnt->barrier->stage->compute)
// with hoisted addressing:
//  - staging: per-thread base pointers hoisted; kt enters ONLY as a compile-time
//    constant folded into the GLOBAL pointer (ga0 + kt*BK), builtin offset = 0.
//    NOTE: the builtin's offset arg applies to BOTH global AND LDS address
//    (LDS_addr = M0 + inst_offset + lane*size) -- R8 used it and scrambled LDS.
//  - compute: swizzle term ssl = lk^((lr>>1)&3) is m-independent, so each
//    ds_read addr = one per-thread base + imm (bsel*8192 + m*1024).
// T5: s_setprio(1) around the 16-MFMA cluster.
__global__ __launch_bounds__(256, 3)
void k_mmd(const short* __restrict__ bfall, const float* __restrict__ sq,
           const float* __restrict__ cvals, double* __restrict__ psum) {
    __shared__ short As[3][BM * BK];   // 3 x 8 KB
    __shared__ short Bs[3][BM * BK];   // 3 x 8 KB
    __shared__ float wred[4];

    // T1: XCD-aware bijective swizzle (NBLK = 8*260), then triangular decode
    int bid = blockIdx.x;
    int swz = (bid & 7) * (NBLK / 8) + (bid >> 3);
    int rem = swz;
    int ti = 0;
    while (rem >= NT - ti) { rem -= NT - ti; ++ti; }
    int tj = ti + rem;

    const int t  = threadIdx.x;
    const int w  = t >> 6;       // wave 0..3
    const int l  = t & 63;
    const int wr = w >> 1, wc = w & 1;
    const int lr = l & 15;       // fragment row/col lane
    const int lk = l >> 4;       // 0..3 k-group (8 bf16 = 1 slot each)

    const int rowA0 = ti * BM, rowB0 = tj * BM;
    const short* gA = bfall + (size_t)rowA0 * NCOLS;
    const short* gB = bfall + (size_t)rowB0 * NCOLS;

    // ---- hoisted staging addresses (kt folds into the global ptr as imm) ----
    const int q0 = t, q1 = 256 + t;
    const int row0 = q0 >> 2, ss0 = (q0 & 3) ^ ((row0 >> 1) & 3);
    const int row1 = q1 >> 2, ss1 = (q1 & 3) ^ ((row1 >> 1) & 3);
    const short* ga0 = gA + (size_t)row0 * NCOLS + ss0 * 8;
    const short* ga1 = gA + (size_t)row1 * NCOLS + ss1 * 8;
    const short* gb0 = gB + (size_t)row0 * NCOLS + ss0 * 8;
    const short* gb1 = gB + (size_t)row1 * NCOLS + ss1 * 8;
    char* dA = (char*)As + q0 * 16;      // dest for q0; q1 dest = dA + 4096
    char* dB = (char*)Bs + q0 * 16;

    // ---- hoisted compute addresses (bsel/m enter as const imm) ----
    const int ssl  = lk ^ ((lr >> 1) & 3);
    const char* pA = (const char*)As + (wr * 64 + lr) * 64 + ssl * 16;
    const char* pB = (const char*)Bs + (wc * 64 + lr) * 64 + ssl * 16;

    // stage tile kt into buffer bsel: 4 global_load_lds per wave -> vmcnt +4
    #define STAGE(bsel, kt)                                                        \
        __builtin_amdgcn_global_load_lds((guint*)(ga0 + (kt) * BK),                \
            (luint*)(dA + (bsel) * 8192), 16, 0, 0);                               \
        __builtin_amdgcn_global_load_lds((guint*)(ga1 + (kt) * BK),                \
            (luint*)(dA + (bsel) * 8192 + 4096), 16, 0, 0);                        \
        __builtin_amdgcn_global_load_lds((guint*)(gb0 + (kt) * BK),                \
            (luint*)(dB + (bsel) * 8192), 16, 0, 0);                               \
        __builtin_amdgcn_global_load_lds((guint*)(gb1 + (kt) * BK),                \
            (luint*)(dB + (bsel) * 8192 + 4096), 16, 0, 0);

    // compute one K-step from buffer bsel: 8 ds_read_b128 + 16 MFMA per wave
    #define COMPUTE(bsel)                                                          \
        {                                                                          \
            s16x8 af[4], bf[4];                                                    \
            _Pragma("unroll")                                                      \
            for (int m = 0; m < 4; ++m)                                            \
                af[m] = *(const s16x8*)(pA + (bsel) * 8192 + m * 1024);            \
            _Pragma("unroll")                                                      \
            for (int n = 0; n < 4; ++n)                                            \
                bf[n] = *(const s16x8*)(pB + (bsel) * 8192 + n * 1024);            \
            __builtin_amdgcn_s_setprio(1);                                         \
            _Pragma("unroll")                                                      \
            for (int m = 0; m < 4; ++m)                                            \
                _Pragma("unroll")                                                  \
                for (int n = 0; n < 4; ++n)                                        \
                    acc[m][n] = __builtin_amdgcn_mfma_f32_16x16x32_bf16(           \
                        af[m], bf[n], acc[m][n], 0, 0, 0);                         \
            __builtin_amdgcn_s_setprio(0);                                         \
        }

    // one pipeline step: wait own stage(kt) landed (kt+1 stays in flight),
    // barrier certifies ALL waves' stage(kt) landed + buffer (kt+2)%3 free,
    // prefetch kt+2, compute kt.
    #define STEP(kt, vm)                                                           \
        asm volatile("s_waitcnt vmcnt(" #vm ")" ::: "memory");                     \
        __builtin_amdgcn_s_barrier();                                              \
        asm volatile("" ::: "memory");                                             \
        if ((kt) + 2 < NKT) { STAGE(((kt) + 2) % 3, (kt) + 2) }                    \
        COMPUTE((kt) % 3)

    f32x4 acc[4][4] = {};

    STAGE(0, 0)
    STAGE(1, 1)        // 8 loads in flight

    STEP(0, 4)  STEP(1, 4)  STEP(2, 4)  STEP(3, 4)
    STEP(4, 4)  STEP(5, 4)  STEP(6, 4)  STEP(7, 4)
    STEP(8, 4)  STEP(9, 4)  STEP(10, 4) STEP(11, 4)
    STEP(12, 4) STEP(13, 4) STEP(14, 4) STEP(15, 0)

    #undef STAGE
    #undef COMPUTE
    #undef STEP

    // ---------- epilogue: l2 -> exp square-chain -> signed/weighted sum ----------
    // (global loads kept AFTER the K-loop so they don't perturb vmcnt counts)
    f32x4 sqa[4];
    #pragma unroll
    for (int m = 0; m < 4; ++m)
        sqa[m] = *(const f32x4*)&sq[rowA0 + wr * 64 + m * 16 + lk * 4];
    float sqb[4];
    #pragma unroll
    for (int n = 0; n < 4; ++n)
        sqb[n] = sq[rowB0 + wc * 64 + n * 16 + lr];
    float c4 = cvals[4];

    const bool diag = (ti == tj);
    const float sgn = ((rowA0 < BHALF) == (rowB0 < BHALF)) ? 1.f : -1.f;
    float local = 0.f;
    #pragma unroll
    for (int m = 0; m < 4; ++m)
        #pragma unroll
        for (int n = 0; n < 4; ++n)
            #pragma unroll
            for (int r = 0; r < 4; ++r) {
                float d  = acc[m][n][r];
                float l2 = sqa[m][r] + sqb[n] - 2.f * d;
                // e_k = exp(-l2/(bw*2^k)) = x^(2^(4-k)), x = 2^(-l2*c4)
                float x  = exp2f(-l2 * c4);
                float x2 = x * x;
                float x4 = x2 * x2;
                float x8 = x4 * x4;
                float e  = x + x2 + x4 + x8 + x8 * x8;
                if (diag) {
                    int gi = rowA0 + wr * 64 + m * 16 + lk * 4 + r;
                    int gj = rowB0 + wc * 64 + n * 16 + lr;
                    float wgt = (gj > gi) ? 2.f : ((gj == gi) ? 1.f : 0.f);
                    local += wgt * e;
                } else {
                    local += e;
                }
            }
    if (!diag) local *= 2.f * sgn;   // diagonal tiles always sgn=+1

    #pragma unroll
    for (int o = 32; o > 0; o >>= 1) local += __shfl_down(local, o);
    if (l == 0) wred[w] = local;
    __syncthreads();
    if (t == 0) {
        psum[blockIdx.x] = (double)(wred[0] + wred[1] + wred[2] + wred[3]);
    }
}

// fixed-order final reduction over NBLK partials -> loss
__global__ void k_final(const double* __restrict__ psum, float* __restrict__ out) {
    __shared__ double red[256];
    int t = threadIdx.x;
    double a = 0.0;
    for (int i = t; i < NBLK; i += 256) a += psum[i];
    red[t] = a; __syncthreads();
    for (int o = 128; o > 0; o >>= 1) { if (t < o) red[t] += red[t + o]; __syncthreads(); }
    if (t == 0) out[0] = (float)(red[0] * (1.0 / ((double)BHALF * (double)BHALF)));
}

// ---------- launch ----------
extern "C" void kernel_launch(void* const* d_in, const int* in_sizes, int n_in,
                              void* d_out, int out_size, void* d_ws, size_t ws_size,
                              hipStream_t stream) {
    (void)in_sizes; (void)n_in; (void)out_size; (void)ws_size;
    const float* src = (const float*)d_in[0];
    const float* tgt = (const float*)d_in[1];
    float* out = (float*)d_out;
    char* ws = (char*)d_ws;
    // layout (all offsets 16B-aligned; every consumed word is rewritten each call):
    short*  bfall  = (short*) (ws);                      // 8192*512*2 = 8388608 B
    float*  sq     = (float*) (ws + 8388608);            // 8192*4 = 32768 B
    float*  cspart = (float*) (ws + 8388608 + 32768);    // 256*512*4 = 524288 B
    float*  cvals  = (float*) (ws + 8388608 + 32768 + 524288);        // 20 B
    double* psum   = (double*)(ws + 8388608 + 32768 + 524288 + 32);   // 2080*8 = 16640 B

    k_conv  <<<CSPART, 256, 0, stream>>>(src, tgt, bfall, sq, cspart);
    k_bw    <<<1, 1024, 0, stream>>>(sq, cspart, cvals);
    k_mmd   <<<NBLK, 256, 0, stream>>>(bfall, sq, cvals, psum);
    k_final <<<1, 256, 0, stream>>>(psum, out);
}